// Round 1
// baseline (18904.144 us; speedup 1.0000x reference)
//
#include <hip/hip_runtime.h>
#include <hip/hip_bf16.h>

#define Bsz 128
#define Tsz 1024
#define Dsz 128
#define Hsz 512
#define NBLK 256
#define NKC 20  // 640 / 32 K-chunks

typedef __attribute__((ext_vector_type(8))) short short8;
typedef __attribute__((ext_vector_type(4))) float floatx4;
typedef __attribute__((ext_vector_type(4))) float f4;

__device__ __forceinline__ short bf16_rne(float f) {
  unsigned u = __builtin_bit_cast(unsigned, f);
  u += 0x7fffu + ((u >> 16) & 1u);
  return (short)(u >> 16);
}
__device__ __forceinline__ float sigmoid_(float v) { return 1.f / (1.f + __expf(-v)); }

__device__ __forceinline__ void wait_flags(const int* flags, int target, int lane) {
  for (;;) {
    int f0 = __hip_atomic_load(flags + lane,       __ATOMIC_RELAXED, __HIP_MEMORY_SCOPE_AGENT);
    int f1 = __hip_atomic_load(flags + lane + 64,  __ATOMIC_RELAXED, __HIP_MEMORY_SCOPE_AGENT);
    int f2 = __hip_atomic_load(flags + lane + 128, __ATOMIC_RELAXED, __HIP_MEMORY_SCOPE_AGENT);
    int f3 = __hip_atomic_load(flags + lane + 192, __ATOMIC_RELAXED, __HIP_MEMORY_SCOPE_AGENT);
    int ok = (f0 >= target) && (f1 >= target) && (f2 >= target) && (f3 >= target);
    if (__all(ok)) break;
    __builtin_amdgcn_s_sleep(1);
  }
}

// Persistent LSTM: 256 blocks (bt 0..7 x ks 0..31), each owns b-tile 16 x k-slice 16.
// Wave w computes gate w's 16x16 preact tile via 20 mfma_16x16x32_bf16, W frags in regs.
// c in registers (1/thread); h bf16 double-buffered in ws; flag-array grid barrier/step.
__global__ __launch_bounds__(256, 1) void lstm_persist(
    const float* __restrict__ x, const float* __restrict__ W_ih,
    const float* __restrict__ W_hh, const float* __restrict__ b_ih,
    const float* __restrict__ b_hh, const float* __restrict__ W_fc,
    const float* __restrict__ b_fc, float* __restrict__ out,
    int* flags, unsigned short* hb0, unsigned short* hb1)
{
  const int bx = blockIdx.x;
  const int ks = bx & 31, bt = bx >> 5;
  const int b0 = bt << 4, k0 = ks << 4;
  const int tx = threadIdx.x;
  const int wave = tx >> 6, lane = tx & 63;
  const int m = lane & 15, quad = lane >> 4;
  const int k_l = tx & 15, b_l = tx >> 4;   // update-phase ownership: (b_l, k_l)

  __shared__ short8 A_lds[NKC][64];      // 20 KB, pre-permuted A fragments
  __shared__ floatx4 gates_lds[4][64];   // 4 KB, per-gate D fragments
  __shared__ float fc_red[16][16];       // final FC reduction

  // ---- load W fragments into registers (once). Wave w = gate w. ----
  short8 wfrag[NKC];
  {
    const int j = wave * Hsz + k0 + m;   // W row = output column n of B-operand
    #pragma unroll
    for (int kc = 0; kc < NKC; ++kc) {
      const int kk = kc * 32 + quad * 8;
      const float* src = (kk < Dsz) ? (W_ih + (size_t)j * Dsz + kk)
                                    : (W_hh + (size_t)j * Hsz + (kk - Dsz));
      const f4* sv = (const f4*)src;
      f4 v0 = sv[0], v1 = sv[1];
      short8 w;
      w[0] = bf16_rne(v0[0]); w[1] = bf16_rne(v0[1]);
      w[2] = bf16_rne(v0[2]); w[3] = bf16_rne(v0[3]);
      w[4] = bf16_rne(v1[0]); w[5] = bf16_rne(v1[1]);
      w[6] = bf16_rne(v1[2]); w[7] = bf16_rne(v1[3]);
      wfrag[kc] = w;
    }
  }
  float bias[4];
  #pragma unroll
  for (int g = 0; g < 4; ++g)
    bias[g] = b_ih[g * Hsz + k0 + k_l] + b_hh[g * Hsz + k0 + k_l];
  float c_reg = 0.f;

  for (int t = 0; t < Tsz; ++t) {
    unsigned short* hnext = (t & 1) ? hb1 : hb0;
    const unsigned short* hprev = (t & 1) ? hb0 : hb1;

    { // stage x chunk (kc = wave, K 0..127): no dependence on h -> before barrier
      const int kc = wave, kk = kc * 32 + quad * 8;
      const f4* sv = (const f4*)(x + (size_t)(b0 + m) * (Tsz * Dsz) + (size_t)t * Dsz + kk);
      f4 v0 = sv[0], v1 = sv[1];
      short8 a;
      a[0] = bf16_rne(v0[0]); a[1] = bf16_rne(v0[1]);
      a[2] = bf16_rne(v0[2]); a[3] = bf16_rne(v0[3]);
      a[4] = bf16_rne(v1[0]); a[5] = bf16_rne(v1[1]);
      a[6] = bf16_rne(v1[2]); a[7] = bf16_rne(v1[3]);
      A_lds[kc][lane] = a;
    }

    if (t > 0) {
      if (wave == 0) wait_flags(flags, t, lane);
      __syncthreads();
      __builtin_amdgcn_fence(__ATOMIC_ACQUIRE, "agent");
      #pragma unroll
      for (int q = 0; q < 4; ++q) {
        const int kc = 4 + wave * 4 + q;
        const int kh = (kc - 4) * 32 + quad * 8;
        A_lds[kc][lane] = *(const short8*)(hprev + (size_t)(b0 + m) * Hsz + kh);
      }
    } else {
      short8 z = {0, 0, 0, 0, 0, 0, 0, 0};
      #pragma unroll
      for (int q = 0; q < 4; ++q) A_lds[4 + wave * 4 + q][lane] = z;
    }
    __syncthreads();

    // ---- K loop: 20 x (ds_read_b128 + mfma). A[m][k] x W[k][n] -> preact[b][k_l]
    floatx4 acc = {0.f, 0.f, 0.f, 0.f};
    #pragma unroll
    for (int kc = 0; kc < NKC; ++kc)
      acc = __builtin_amdgcn_mfma_f32_16x16x32_bf16(A_lds[kc][lane], wfrag[kc], acc, 0, 0, 0);

    gates_lds[wave][lane] = acc;   // lane holds D[b=quad*4+r][n=lane&15]
    __syncthreads();

    { // ---- gate combine + state update: thread owns (b_l, k_l) ----
      const int lp = ((b_l >> 2) << 4) + k_l;  // lane holding row b_l
      const int r = b_l & 3;                   // reg index
      float pi = gates_lds[0][lp][r] + bias[0];
      float pf = gates_lds[1][lp][r] + bias[1];
      float pg = gates_lds[2][lp][r] + bias[2];
      float po = gates_lds[3][lp][r] + bias[3];
      float iv = sigmoid_(pi), fv = sigmoid_(pf), ov = sigmoid_(po);
      float gv = tanhf(pg);
      c_reg = fv * c_reg + iv * gv;
      float hv = ov * tanhf(c_reg);
      hnext[(size_t)(b0 + b_l) * Hsz + k0 + k_l] = (unsigned short)bf16_rne(hv);
    }
    __syncthreads();               // drains vmcnt: all waves' h stores in L2
    if (tx == 0) {
      __builtin_amdgcn_fence(__ATOMIC_RELEASE, "agent");  // L2 writeback -> LLC
      __hip_atomic_store(flags + bx, t + 1, __ATOMIC_RELAXED, __HIP_MEMORY_SCOPE_AGENT);
    }
  }

  // ---- final FC: out[b] = sigmoid(h_last . W_fc + b_fc), done by ks==0 blocks ----
  if (ks == 0) {
    if (wave == 0) wait_flags(flags, Tsz, lane);
    __syncthreads();
    __builtin_amdgcn_fence(__ATOMIC_ACQUIRE, "agent");
    const unsigned short* hl = hb1;  // t=1023 (odd) wrote hb1
    const unsigned short* hp = hl + (size_t)(b0 + b_l) * Hsz + k_l * 32;
    float partial = 0.f;
    #pragma unroll
    for (int e = 0; e < 32; ++e)
      partial += __builtin_bit_cast(float, ((unsigned)hp[e]) << 16) * W_fc[k_l * 32 + e];
    fc_red[b_l][k_l] = partial;
    __syncthreads();
    if (k_l == 0) {
      float s = b_fc[0];
      #pragma unroll
      for (int e = 0; e < 16; ++e) s += fc_red[b_l][e];
      out[b0 + b_l] = sigmoid_(s);
    }
  }
}

extern "C" void kernel_launch(void* const* d_in, const int* in_sizes, int n_in,
                              void* d_out, int out_size, void* d_ws, size_t ws_size,
                              hipStream_t stream) {
  const float* x    = (const float*)d_in[0];
  const float* W_ih = (const float*)d_in[1];
  const float* W_hh = (const float*)d_in[2];
  const float* b_ih = (const float*)d_in[3];
  const float* b_hh = (const float*)d_in[4];
  const float* W_fc = (const float*)d_in[5];
  const float* b_fc = (const float*)d_in[6];
  float* out = (float*)d_out;
  char* ws = (char*)d_ws;
  int* flags = (int*)ws;                                   // 256 x int, zeroed below
  unsigned short* hb0 = (unsigned short*)(ws + 4096);      // h double buffer (bf16)
  unsigned short* hb1 = (unsigned short*)(ws + 4096 + (size_t)Bsz * Hsz * 2);
  hipMemsetAsync(ws, 0, 4096, stream);                     // barrier flags := 0
  lstm_persist<<<NBLK, 256, 0, stream>>>(x, W_ih, W_hh, b_ih, b_hh, W_fc, b_fc,
                                         out, flags, hb0, hb1);
}

// Round 2
// 3123.539 us; speedup vs baseline: 6.0522x; 6.0522x over previous
//
#include <hip/hip_runtime.h>
#include <hip/hip_bf16.h>

#define Bsz 128
#define Tsz 1024
#define Dsz 128
#define Hsz 512
#define NBLK 256
#define NKC 20  // 640 / 32 K-chunks

typedef __attribute__((ext_vector_type(8))) short short8;
typedef __attribute__((ext_vector_type(4))) float f4;
typedef unsigned long long u64;

__device__ __forceinline__ short bf16_rne(float f) {
  unsigned u = __builtin_bit_cast(unsigned, f);
  u += 0x7fffu + ((u >> 16) & 1u);
  return (short)(u >> 16);
}
__device__ __forceinline__ float sigmoid_(float v) { return 1.f / (1.f + __expf(-v)); }

// Persistent LSTM, fence-free coherence:
//  - h + flags exchanged via agent-scope RELAXED atomics (bypass L1/L2 -> LLC).
//    No buffer_wbl2 / buffer_inv per step => x stays cached in L2.
//  - 8 independent bt-groups of 32 blocks; bt = bx&7 so a group maps to one XCD
//    under round-robin dispatch (perf heuristic only; agent scope keeps it correct).
//  - Ordering: __syncthreads() drains vmcnt before the flag store; readers issue
//    h loads only after the flag load returns (both hit the LLC coherence point).
__global__ __launch_bounds__(256, 1) void lstm_persist(
    const float* __restrict__ x, const float* __restrict__ W_ih,
    const float* __restrict__ W_hh, const float* __restrict__ b_ih,
    const float* __restrict__ b_hh, const float* __restrict__ W_fc,
    const float* __restrict__ b_fc, float* __restrict__ out,
    int* flags, unsigned short* hb0, unsigned short* hb1)
{
  const int bx = blockIdx.x;
  const int bt = bx & 7, ks = bx >> 3;   // group = same bt (same XCD if round-robin)
  const int b0 = bt << 4, k0 = ks << 4;
  const int tx = threadIdx.x;
  const int wave = tx >> 6, lane = tx & 63;
  const int m = lane & 15, quad = lane >> 4;
  const int k_l = tx & 15, b_l = tx >> 4;   // update-phase ownership: (b_l, k_l)

  __shared__ short8 A_lds[NKC][64];      // 20 KB, pre-permuted A fragments
  __shared__ f4 gates_lds[4][64];        // 4 KB, per-gate D fragments
  __shared__ float fc_red[16][16];       // final FC reduction

  int* gflags = flags + bt * 32;         // 32 flags = 128 B, one group

  // ---- load W fragments into registers (once). Wave w = gate w. ----
  short8 wfrag[NKC];
  {
    const int j = wave * Hsz + k0 + m;   // W row = output column n of B-operand
    #pragma unroll
    for (int kc = 0; kc < NKC; ++kc) {
      const int kk = kc * 32 + quad * 8;
      const float* src = (kk < Dsz) ? (W_ih + (size_t)j * Dsz + kk)
                                    : (W_hh + (size_t)j * Hsz + (kk - Dsz));
      const f4* sv = (const f4*)src;
      f4 v0 = sv[0], v1 = sv[1];
      short8 w;
      w[0] = bf16_rne(v0[0]); w[1] = bf16_rne(v0[1]);
      w[2] = bf16_rne(v0[2]); w[3] = bf16_rne(v0[3]);
      w[4] = bf16_rne(v1[0]); w[5] = bf16_rne(v1[1]);
      w[6] = bf16_rne(v1[2]); w[7] = bf16_rne(v1[3]);
      wfrag[kc] = w;
    }
  }
  float bias[4];
  #pragma unroll
  for (int g = 0; g < 4; ++g)
    bias[g] = b_ih[g * Hsz + k0 + k_l] + b_hh[g * Hsz + k0 + k_l];
  float c_reg = 0.f;

  for (int t = 0; t < Tsz; ++t) {
    unsigned short* hnext = (t & 1) ? hb1 : hb0;
    const unsigned short* hprev = (t & 1) ? hb0 : hb1;

    // Issue x loads first: in flight (normal, L2-cached) while we poll.
    const f4* xv = (const f4*)(x + (size_t)(b0 + m) * (Tsz * Dsz)
                               + (size_t)t * Dsz + wave * 32 + quad * 8);
    f4 v0 = xv[0], v1 = xv[1];

    if (t > 0) {
      // all 4 waves poll the 32 group flags (lanes 32..63 mirror 0..31)
      for (;;) {
        int f = __hip_atomic_load(gflags + (lane & 31),
                                  __ATOMIC_RELAXED, __HIP_MEMORY_SCOPE_AGENT);
        if (__all(f >= t)) break;
        __builtin_amdgcn_s_sleep(1);
      }
      // stage this wave's 4 h chunks from LLC (agent-scope loads, bypass L2)
      #pragma unroll
      for (int q = 0; q < 4; ++q) {
        const int kc = 4 + wave * 4 + q;
        const int kh = (kc - 4) * 32 + quad * 8;
        const u64* p = (const u64*)(hprev + (size_t)(b0 + m) * Hsz + kh);
        u64 lo = __hip_atomic_load(p,     __ATOMIC_RELAXED, __HIP_MEMORY_SCOPE_AGENT);
        u64 hi = __hip_atomic_load(p + 1, __ATOMIC_RELAXED, __HIP_MEMORY_SCOPE_AGENT);
        u64* dst = (u64*)&A_lds[kc][lane];
        dst[0] = lo; dst[1] = hi;
      }
    } else {
      short8 z = {0, 0, 0, 0, 0, 0, 0, 0};
      #pragma unroll
      for (int q = 0; q < 4; ++q) A_lds[4 + wave * 4 + q][lane] = z;
    }

    { // stage x chunk (kc = wave, K 0..127)
      short8 a;
      a[0] = bf16_rne(v0[0]); a[1] = bf16_rne(v0[1]);
      a[2] = bf16_rne(v0[2]); a[3] = bf16_rne(v0[3]);
      a[4] = bf16_rne(v1[0]); a[5] = bf16_rne(v1[1]);
      a[6] = bf16_rne(v1[2]); a[7] = bf16_rne(v1[3]);
      A_lds[wave][lane] = a;
    }
    __syncthreads();

    // ---- K loop: 20 x (ds_read_b128 + mfma), 2 accumulators for ILP
    f4 acc0 = {0.f, 0.f, 0.f, 0.f}, acc1 = {0.f, 0.f, 0.f, 0.f};
    #pragma unroll
    for (int kc = 0; kc < NKC; kc += 2) {
      acc0 = __builtin_amdgcn_mfma_f32_16x16x32_bf16(A_lds[kc][lane],     wfrag[kc],     acc0, 0, 0, 0);
      acc1 = __builtin_amdgcn_mfma_f32_16x16x32_bf16(A_lds[kc + 1][lane], wfrag[kc + 1], acc1, 0, 0, 0);
    }
    gates_lds[wave][lane] = acc0 + acc1;   // lane holds D[b=quad*4+r][n=lane&15]
    __syncthreads();

    { // ---- gate combine + state update: thread owns (b_l, k_l) ----
      const int lp = ((b_l >> 2) << 4) + k_l;  // lane holding row b_l
      const int r = b_l & 3;                   // reg index
      float pi = gates_lds[0][lp][r] + bias[0];
      float pf = gates_lds[1][lp][r] + bias[1];
      float pg = gates_lds[2][lp][r] + bias[2];
      float po = gates_lds[3][lp][r] + bias[3];
      float iv = sigmoid_(pi), fv = sigmoid_(pf), ov = sigmoid_(po);
      float gv = tanhf(pg);
      c_reg = fv * c_reg + iv * gv;
      float hv = ov * tanhf(c_reg);
      // pack two bf16 (k_l even|odd) into one u32 agent-scope store (no 16b atomics)
      unsigned hbits = (unsigned)(unsigned short)bf16_rne(hv);
      unsigned obits = __shfl_xor(hbits, 1);
      if ((k_l & 1) == 0) {
        unsigned packed = hbits | (obits << 16);
        unsigned* p = (unsigned*)(hnext + (size_t)(b0 + b_l) * Hsz + k0 + k_l);
        __hip_atomic_store(p, packed, __ATOMIC_RELAXED, __HIP_MEMORY_SCOPE_AGENT);
      }
    }
    __syncthreads();               // drains vmcnt: all waves' h stores at LLC
    if (tx == 0)
      __hip_atomic_store(gflags + ks, t + 1, __ATOMIC_RELAXED, __HIP_MEMORY_SCOPE_AGENT);
  }

  // ---- final FC: out[b] = sigmoid(h_last . W_fc + b_fc), ks==0 blocks ----
  if (ks == 0) {
    for (;;) {
      int f = __hip_atomic_load(gflags + (lane & 31),
                                __ATOMIC_RELAXED, __HIP_MEMORY_SCOPE_AGENT);
      if (__all(f >= Tsz)) break;
      __builtin_amdgcn_s_sleep(1);
    }
    const unsigned short* hl = hb1;  // t=1023 (odd) wrote hb1
    const u64* p = (const u64*)(hl + (size_t)(b0 + b_l) * Hsz + k_l * 32);
    float partial = 0.f;
    #pragma unroll
    for (int q = 0; q < 8; ++q) {
      u64 v = __hip_atomic_load(p + q, __ATOMIC_RELAXED, __HIP_MEMORY_SCOPE_AGENT);
      #pragma unroll
      for (int e = 0; e < 4; ++e) {
        unsigned hv16 = (unsigned)((v >> (16 * e)) & 0xffffu);
        partial += __builtin_bit_cast(float, hv16 << 16) * W_fc[k_l * 32 + q * 4 + e];
      }
    }
    fc_red[b_l][k_l] = partial;
    __syncthreads();
    if (k_l == 0) {
      float s = b_fc[0];
      #pragma unroll
      for (int e = 0; e < 16; ++e) s += fc_red[b_l][e];
      out[b0 + b_l] = sigmoid_(s);
    }
  }
}

extern "C" void kernel_launch(void* const* d_in, const int* in_sizes, int n_in,
                              void* d_out, int out_size, void* d_ws, size_t ws_size,
                              hipStream_t stream) {
  const float* x    = (const float*)d_in[0];
  const float* W_ih = (const float*)d_in[1];
  const float* W_hh = (const float*)d_in[2];
  const float* b_ih = (const float*)d_in[3];
  const float* b_hh = (const float*)d_in[4];
  const float* W_fc = (const float*)d_in[5];
  const float* b_fc = (const float*)d_in[6];
  float* out = (float*)d_out;
  char* ws = (char*)d_ws;
  int* flags = (int*)ws;                                   // 8 groups x 32 flags
  unsigned short* hb0 = (unsigned short*)(ws + 4096);      // h double buffer (bf16)
  unsigned short* hb1 = (unsigned short*)(ws + 4096 + (size_t)Bsz * Hsz * 2);
  hipMemsetAsync(ws, 0, 4096, stream);                     // barrier flags := 0
  lstm_persist<<<NBLK, 256, 0, stream>>>(x, W_ih, W_hh, b_ih, b_hh, W_fc, b_fc,
                                         out, flags, hb0, hb1);
}